// Round 13
// baseline (308.259 us; speedup 1.0000x reference)
//
#include <hip/hip_runtime.h>
#include <stdint.h>

constexpr int kN = 16384;
constexpr int kD = 256;
constexpr int TM = 256, TN = 256;   // block tile 256x256
constexpr int KB = kD / 2;          // fp4 row = 128 bytes

using floatx16 = __attribute__((ext_vector_type(16))) float;  // 32x32 MFMA C/D
using floatx2  = __attribute__((ext_vector_type(2))) float;   // v_pk_* pair
using intx2v   = __attribute__((ext_vector_type(2))) int;
using intx4    = __attribute__((ext_vector_type(4))) int;
using intx8    = __attribute__((ext_vector_type(8))) int;     // f8f6f4 operand

// fp32*16 -> fp4 e2m1 RNE. Codes 0..7 = {0,.5,1,1.5,2,3,4,6} ARE the bit
// patterns (monotone). Thresholds are the RNE midpoints. (R12-verified.)
__device__ __forceinline__ uint32_t q4(float x) {
    float y = fabsf(x * 16.f);
    uint32_t c = (y >= 0.25f) + (y >= 0.75f) + (y >= 1.25f) + (y >= 1.75f)
               + (y >= 2.5f)  + (y >= 3.5f)  + (y >= 5.0f);
    return c | (x < 0.f ? 8u : 0u);
}

// A row-major; B CHUNK-MAJOR B'[c][row] (c = 16B K-chunk) via small LDS
// regroup -> coalesced 128B store runs (R23 cvt, refcheck'd absmax 0.0).
__global__ __launch_bounds__(256)
void cvt_fp4_kernel(const float* __restrict__ a, const float* __restrict__ b,
                    unsigned int* __restrict__ oa, unsigned int* __restrict__ ob,
                    float* __restrict__ out) {
    __shared__ uint32_t lb[8][36];
    const int t = threadIdx.x;
    const int idx = blockIdx.x * 256 + t;
    if (idx == 0) *out = 0.f;
    float4 a0 = *(const float4*)(a + (size_t)idx * 8);
    float4 a1 = *(const float4*)(a + (size_t)idx * 8 + 4);
    float4 b0 = *(const float4*)(b + (size_t)idx * 8);
    float4 b1 = *(const float4*)(b + (size_t)idx * 8 + 4);
    uint32_t pa = q4(a0.x) | (q4(a0.y) << 4) | (q4(a0.z) << 8)  | (q4(a0.w) << 12)
                | (q4(a1.x) << 16) | (q4(a1.y) << 20) | (q4(a1.z) << 24) | (q4(a1.w) << 28);
    uint32_t pb = q4(b0.x) | (q4(b0.y) << 4) | (q4(b0.z) << 8)  | (q4(b0.w) << 12)
                | (q4(b1.x) << 16) | (q4(b1.y) << 20) | (q4(b1.z) << 24) | (q4(b1.w) << 28);
    oa[idx] = pa;
    const int row = t >> 5, d = t & 31;
    lb[row][(d >> 2) * 4 + (d & 3)] = pb;
    __syncthreads();
    const int c2 = t >> 5, r2 = (t >> 2) & 7, w2 = t & 3;
    ob[((size_t)c2 * kN + blockIdx.x * 8 + r2) * 4 + w2] = lb[r2][c2 * 4 + w2];
}

// Undef-high 8-reg tuple from one 4-reg quad: fp4 MFMA reads only v[0:3]
// (HW-validated R14-R25: absmax 0.0).
#define U8(v)  __builtin_shufflevector((v), (v), 0, 1, 2, 3, -1, -1, -1, -1)
#define MFMA4(a, b, c) __builtin_amdgcn_mfma_scale_f32_32x32x64_f8f6f4( \
        (a), (b), (c), 4 /*cbsz fp4*/, 4 /*blgp fp4*/, 0, 127, 0, 127)

// async global->LDS, 16B per lane. LDS dst = wave-uniform base + lane*16.
__device__ __forceinline__ void gl2lds16(const unsigned char* g, unsigned char* l) {
    __builtin_amdgcn_global_load_lds(
        (const __attribute__((address_space(1))) unsigned int*)g,
        (__attribute__((address_space(3))) unsigned int*)l, 16, 0, 0);
}

// R26: CROSS-TILE epilogue weave at ZERO register cost. Consolidated facts:
// R21 == R22 == R24 == 48.6us, MfmaUtil 27-29%, clean gates -- chain shape,
// SGB pinning, spacing all null. Untested cheap variable: in every clean
// round, E(s) runs strictly AFTER M(s) (data dep) and both waves take the
// phases together -> timeline [M 2048][E ~3000][dead ~2200] per SIMD-tile.
// This round: weave E(s-1) into the q0 round of M(s) -- block bk's acc is
// epilogued+reset immediately BEFORE its own q0 MFMA:
//   for bk: { epiB(bk, prevCol); mfma_q0(bk); }   then q1..q3 pure rounds.
// E(s-1) has no dep on M(s); live ranges are IDENTICAL to R24 (epi reads
// meet the same deadline R24's reset met; no new buffers, no duplication)
// -> no spill vector. Model: phase1 = 1024cy VALU/SIMD with 16 q0-MFMAs
// hidden, phase2 = 48 MFMAs = 1536cy pipe-dense -> ~3000cy/tile vs 7290.
// Pre-commit: gates pass but GEMM >= 42us / MfmaUtil <= 33% => schedule-
// structure class EXHAUSTED; limiter is per-wave MFMA issue/latency at
// 2 waves/SIMD; R27 pivots to 4 waves/SIMD + LDS operand streaming.
__global__ __launch_bounds__(512, 2)
void siglip_gemm_loss_kernel(const unsigned char* __restrict__ A,   // fp4 [N][KB]
                             const unsigned char* __restrict__ Bc,  // fp4 chunk-major
                             const float* __restrict__ scale_p,
                             const float* __restrict__ bias_p,
                             float* __restrict__ out) {
    __shared__ unsigned char ldsB[8][2][8192];   // [wave][buf][chunk-major 8x64x16B]
    __shared__ float red[8];

    const int tid  = threadIdx.x;
    const int wave = tid >> 6;     // 0..7
    const int lane = tid & 63;

    const int g    = blockIdx.x;                  // 256 persistent blocks
    const int tRow = ((g & 7) << 3) + (g >> 5);   // fixed tile-row (A-stripe L2-hot)
    const int sCol = (g >> 3) & 3;                // tile s -> col sCol + 4s

    const int wr = wave >> 2, wc = wave & 3;   // 2x4 waves
    const int m0 = wr * 128, n0 = wc * 64;     // wave tile 128x64
    const int l31 = lane & 31;
    const int h   = lane >> 5;                 // K-half: byte offset 16h

    const float sc  = *scale_p * (1.0f / 256.0f);   // undo x16 x16 prescale
    const float bs  = *bias_p;
    const float sc3 = sc * (1.44269504f * 8388608.0f);
    const float bs3 = fmaf(bs, 1.44269504f * 8388608.0f, 1064986823.0f);
    const floatx2 sc3v = (floatx2)(sc3);
    const floatx2 bs3v = (floatx2)(bs3);

    // ---- A operand: loop-invariant, resident as raw intx4 quads (row-major A).
    intx4 af[4][4];
    #pragma unroll
    for (int i = 0; i < 4; ++i) {
        const unsigned char* pa = A + ((size_t)tRow * TM + m0 + i * 32 + l31) * KB + 16 * h;
        #pragma unroll
        for (int q = 0; q < 4; ++q)
            af[i][q] = *(const intx4*)(pa + q * 32);
    }

    floatx16 acc[4][2];             // 8 independent chains, 128 AGPR (R13 shape)
    #pragma unroll
    for (int i = 0; i < 4; ++i)
        #pragma unroll
        for (int j = 0; j < 2; ++j) acc[i][j] = (floatx16)(0.f);
    floatx2 sm0 = (floatx2)(0.f), sm1 = (floatx2)(0.f);
    float smd = 0.f;                // diagonal correction accumulator

    // ---- staging: chunk i (16B of K) for the wave's 64 B-rows (R21-proven).
    const unsigned char* pSrcLane =
        Bc + ((size_t)(sCol * TN + n0) + lane) * 16;
    auto stageT = [&](const int s) {
        const unsigned char* src = pSrcLane + (size_t)s * (4 * TN * 16);
        unsigned char* dst = &ldsB[wave][s & 1][0];
        #pragma unroll
        for (int i = 0; i < 8; ++i)
            gl2lds16(src + (size_t)i * (kN * 16), dst + i * 1024);
    };

    // ---- B tile read: quad (j,q) = chunk c=2q+h, row j*32+l31 (conflict-free).
    intx4 bl[2][4];
    auto ldsLoadT = [&](const int s) {
        const unsigned char* base = &ldsB[wave][s & 1][h * 1024 + l31 * 16];
        #pragma unroll
        for (int j = 0; j < 2; ++j)
            #pragma unroll
            for (int q = 0; q < 4; ++q)
                bl[j][q] = *(const intx4*)(base + q * 2048 + j * 512);
    };

    // one epi slice: 4 elems starting at vb (2 pk_fma + 4 cvt + 2 pk_add)
    auto epiQ = [&](const floatx16& ae, const int vb) {
        floatx2 t0 = {ae[vb + 0], ae[vb + 1]};
        floatx2 t1 = {ae[vb + 2], ae[vb + 3]};
        t0 = __builtin_elementwise_fma(t0, sc3v, bs3v);  // v_pk_fma_f32
        t1 = __builtin_elementwise_fma(t1, sc3v, bs3v);
        const intx2v e0 = {(int)t0.x, (int)t0.y};        // v_cvt_i32_f32
        const intx2v e1 = {(int)t1.x, (int)t1.y};
        sm0 += __builtin_bit_cast(floatx2, e0);          // v_pk_add_f32
        sm1 += __builtin_bit_cast(floatx2, e1);
    };

    // epilogue + reset of ONE block (i,j) for tile-col tCol (R24 semantics).
    auto epiB = [&](const int i, const int j, const int tCol) {
        epiQ(acc[i][j], 0); epiQ(acc[i][j], 4);
        epiQ(acc[i][j], 8); epiQ(acc[i][j], 12);
        const int gRow0 = tRow * TM + m0 + i * 32;
        const int gCol0 = tCol * TN + n0 + j * 32;
        if (gRow0 == gCol0) {   // wave-uniform, rare
            #pragma unroll
            for (int v = 0; v < 16; ++v) {
                const int rrow = (v & 3) + 8 * (v >> 2) + 4 * h;
                if (rrow == l31) smd += fmaf(acc[i][j][v], sc, bs);
            }
        }
        acc[i][j] = (floatx16)(0.f);
    };

    // ---- main loop: barrier-free vmcnt-counted staging.
    // Per tile s: E(s-1) woven into the q0 round block-by-block, then pure
    // q1..q3 rounds (q-outer, 8 independent MFMAs per round).
    stageT(0);
    for (int s = 0; s < 16; ++s) {
        if (s < 15) {
            stageT(s + 1);                                   // 8 more in flight
            asm volatile("s_waitcnt vmcnt(8)" ::: "memory"); // stage(s) landed
        } else {
            asm volatile("s_waitcnt vmcnt(0)" ::: "memory");
        }
        ldsLoadT(s);                // 8 ds_read_b128, conflict-free
        const int cP = sCol + 4 * (s - 1);
        // q0 round with woven E(s-1): epi(bk) right before q0-MFMA(bk)
        #pragma unroll
        for (int bk = 0; bk < 8; ++bk) {
            const int i = bk >> 1, j = bk & 1;
            if (s > 0) epiB(i, j, cP);          // 32 VALU, no dep on M(s)
            acc[i][j] = MFMA4(U8(af[i][0]), U8(bl[j][0]), acc[i][j]);
        }
        // q1..q3: pipe-dense rounds
        #pragma unroll
        for (int q = 1; q < 4; ++q)
            #pragma unroll
            for (int i = 0; i < 4; ++i)
                #pragma unroll
                for (int j = 0; j < 2; ++j)
                    acc[i][j] = MFMA4(U8(af[i][q]), U8(bl[j][q]), acc[i][j]);
    }
    // drain tile 15's epilogues
    #pragma unroll
    for (int bk = 0; bk < 8; ++bk)
        epiB(bk >> 1, bk & 1, sCol + 60);

    float sum = (sm0.x + sm1.x) + (sm0.y + sm1.y) - smd;

    // block reduce -> ONE atomicAdd per block (256 total, spread in time)
    #pragma unroll
    for (int off = 32; off > 0; off >>= 1)
        sum += __shfl_down(sum, off);
    if (lane == 0) red[wave] = sum;
    __syncthreads();
    if (tid == 0) {
        float s2 = 0.f;
        #pragma unroll
        for (int w = 0; w < 8; ++w) s2 += red[w];
        atomicAdd(out, s2 * (1.0f / (float)kN));
    }
}

extern "C" void kernel_launch(void* const* d_in, const int* in_sizes, int n_in,
                              void* d_out, int out_size, void* d_ws, size_t ws_size,
                              hipStream_t stream) {
    const float* img     = (const float*)d_in[0];
    const float* txt     = (const float*)d_in[1];
    const float* scale_p = (const float*)d_in[2];
    const float* bias_p  = (const float*)d_in[3];
    float* out = (float*)d_out;

    unsigned char* Af4 = (unsigned char*)d_ws;            // N*KB = 2 MiB (row-major)
    unsigned char* Bf4 = Af4 + (size_t)kN * KB;           // 2 MiB (chunk-major)

    cvt_fp4_kernel<<<dim3(kN * kD / 8 / 256), dim3(256), 0, stream>>>(
        img, txt, (unsigned int*)Af4, (unsigned int*)Bf4, out);
    siglip_gemm_loss_kernel<<<dim3(256), dim3(512), 0, stream>>>(
        Af4, Bf4, scale_p, bias_p, out);
}

// Round 14
// 128.602 us; speedup vs baseline: 2.3970x; 2.3970x over previous
//
#include <hip/hip_runtime.h>
#include <stdint.h>

constexpr int kN = 16384;
constexpr int kD = 256;
constexpr int KB = kD / 2;          // fp4 row = 128 bytes

using floatx16 = __attribute__((ext_vector_type(16))) float;  // 32x32 MFMA C/D
using floatx2  = __attribute__((ext_vector_type(2))) float;   // v_pk_* pair
using intx2v   = __attribute__((ext_vector_type(2))) int;
using intx4    = __attribute__((ext_vector_type(4))) int;
using intx8    = __attribute__((ext_vector_type(8))) int;     // f8f6f4 operand

// fp32*16 -> fp4 e2m1 RNE. Codes 0..7 = {0,.5,1,1.5,2,3,4,6} ARE the bit
// patterns (monotone). Thresholds are the RNE midpoints. (R12-verified.)
__device__ __forceinline__ uint32_t q4(float x) {
    float y = fabsf(x * 16.f);
    uint32_t c = (y >= 0.25f) + (y >= 0.75f) + (y >= 1.25f) + (y >= 1.75f)
               + (y >= 2.5f)  + (y >= 3.5f)  + (y >= 5.0f);
    return c | (x < 0.f ? 8u : 0u);
}

// A row-major; B CHUNK-MAJOR B'[c][row] (c = 16B K-chunk) via small LDS
// regroup -> coalesced 128B store runs (R23 cvt, refcheck'd absmax 0.0).
__global__ __launch_bounds__(256)
void cvt_fp4_kernel(const float* __restrict__ a, const float* __restrict__ b,
                    unsigned int* __restrict__ oa, unsigned int* __restrict__ ob,
                    float* __restrict__ out) {
    __shared__ uint32_t lb[8][36];
    const int t = threadIdx.x;
    const int idx = blockIdx.x * 256 + t;
    if (idx == 0) *out = 0.f;
    float4 a0 = *(const float4*)(a + (size_t)idx * 8);
    float4 a1 = *(const float4*)(a + (size_t)idx * 8 + 4);
    float4 b0 = *(const float4*)(b + (size_t)idx * 8);
    float4 b1 = *(const float4*)(b + (size_t)idx * 8 + 4);
    uint32_t pa = q4(a0.x) | (q4(a0.y) << 4) | (q4(a0.z) << 8)  | (q4(a0.w) << 12)
                | (q4(a1.x) << 16) | (q4(a1.y) << 20) | (q4(a1.z) << 24) | (q4(a1.w) << 28);
    uint32_t pb = q4(b0.x) | (q4(b0.y) << 4) | (q4(b0.z) << 8)  | (q4(b0.w) << 12)
                | (q4(b1.x) << 16) | (q4(b1.y) << 20) | (q4(b1.z) << 24) | (q4(b1.w) << 28);
    oa[idx] = pa;
    const int row = t >> 5, d = t & 31;
    lb[row][(d >> 2) * 4 + (d & 3)] = pb;
    __syncthreads();
    const int c2 = t >> 5, r2 = (t >> 2) & 7, w2 = t & 3;
    ob[((size_t)c2 * kN + blockIdx.x * 8 + r2) * 4 + w2] = lb[r2][c2 * 4 + w2];
}

// Undef-high 8-reg tuple from one 4-reg quad: fp4 MFMA reads only v[0:3]
// (HW-validated R14-R26: absmax 0.0).
#define U8(v)  __builtin_shufflevector((v), (v), 0, 1, 2, 3, -1, -1, -1, -1)
#define MFMA4(a, b, c) __builtin_amdgcn_mfma_scale_f32_32x32x64_f8f6f4( \
        (a), (b), (c), 4 /*cbsz fp4*/, 4 /*blgp fp4*/, 0, 127, 0, 127)

// async global->LDS, 16B per lane. LDS dst = wave-uniform base + lane*16.
__device__ __forceinline__ void gl2lds16(const unsigned char* g, unsigned char* l) {
    __builtin_amdgcn_global_load_lds(
        (const __attribute__((address_space(1))) unsigned int*)g,
        (__attribute__((address_space(3))) unsigned int*)l, 16, 0, 0);
}

// R27: 4 waves/SIMD from INDEPENDENT blocks. R14-R26 verdict: any in-wave
// epi<->MFMA interleave spills at the 2-wave (256-reg) budget; the
// non-spilling phase-separated shape is pinned at 27-29% MfmaUtil because
// its 2 SIMD-mate waves are lockstep -- both pipes take turns idling. m114:
// cross-wave MFMA||VALU overlap is free -- we just never had enough
// independent wave streams. This round: 256-thread blocks,
// __launch_bounds__(256,4) -> 4 blocks/CU -> each SIMD hosts 4 waves from
// 4 DIFFERENT blocks (a block's 4 waves land one-per-SIMD), naturally
// desynced. Per-wave working set cut to fit the 128-reg cap WITH MARGIN:
// wave tile 32x64 -> acc[2] 32 + af[4] 16 + bl[2][4] 32 + misc ~= 108.
// At <=128 unified regs acc stays in VGPRs -> no accvgpr-read epi tax.
// B: wave-private SINGLE-buffered 8KB LDS slice (4x8KB+red = 32.8KB/block,
// 4 blocks/CU fits 160KB). Barrier-free: within-wave order
// ldsLoad(s); lgkmcnt(0); stage(s+1); M(s); E(s) is WAR-safe (reads done
// before rewrite issues), and vmcnt(0) at tile top sits ~M+E after issue.
// Grid 1024 = 128 row-stripes x 8 col-groups (cg ~ XCD: 256KB B slice
// L2-resident/XCD); 32 col-tiles per block, col n0 = (cg + 8s)*64.
// Pre-commit: occupancy ~50% + clean gates but GEMM >= 42us / MfmaUtil
// <= 35% => TLP falsified; next round cuts epilogue op count itself.
__global__ __launch_bounds__(256, 4)
void siglip_gemm_loss_kernel(const unsigned char* __restrict__ A,   // fp4 [N][KB]
                             const unsigned char* __restrict__ Bc,  // fp4 chunk-major
                             const float* __restrict__ scale_p,
                             const float* __restrict__ bias_p,
                             float* __restrict__ out) {
    __shared__ unsigned char ldsB[4][8192];   // [wave][chunk-major 8x64x16B]
    __shared__ float red[4];

    const int tid  = threadIdx.x;
    const int wave = tid >> 6;     // 0..3
    const int lane = tid & 63;

    const int g      = blockIdx.x;       // 1024 persistent blocks (4/CU)
    const int stripe = g >> 3;           // row-stripe 0..127 (128 rows each)
    const int cg     = g & 7;            // col-group ~ XCD (L2-resident B slice)

    const int l31 = lane & 31;
    const int h   = lane >> 5;           // K-half: byte offset 16h
    const int rowBase = stripe * 128 + wave * 32;   // wave's 32 A-rows

    const float sc  = *scale_p * (1.0f / 256.0f);   // undo x16 x16 prescale
    const float bs  = *bias_p;
    const float sc3 = sc * (1.44269504f * 8388608.0f);
    const float bs3 = fmaf(bs, 1.44269504f * 8388608.0f, 1064986823.0f);
    const floatx2 sc3v = (floatx2)(sc3);
    const floatx2 bs3v = (floatx2)(bs3);

    // ---- A operand: loop-invariant, 32 rows x full K = 4 quads (16 regs).
    intx4 af[4];
    {
        const unsigned char* pa = A + (size_t)(rowBase + l31) * KB + 16 * h;
        #pragma unroll
        for (int q = 0; q < 4; ++q)
            af[q] = *(const intx4*)(pa + q * 32);
    }

    floatx16 acc[2];                // 32x64 wave tile: 2 blocks of 32x32
    acc[0] = (floatx16)(0.f);
    acc[1] = (floatx16)(0.f);
    floatx2 sm0 = (floatx2)(0.f), sm1 = (floatx2)(0.f);
    float smd = 0.f;                // diagonal correction accumulator

    // ---- staging: tile s covers B-rows n0 = (cg + 8s)*64 .. +64.
    // chunk-major: chunk i, row r at Bc + (i*kN + r)*16. Per chunk one
    // gl2lds16 (64 lanes x 16B = 1KB contiguous). Tile advance: +512 rows.
    const unsigned char* pSrcLane = Bc + (size_t)(cg * 64 + lane) * 16;
    auto stageT = [&](const int s) {
        const unsigned char* src = pSrcLane + (size_t)s * (512 * 16);
        unsigned char* dst = &ldsB[wave][0];
        #pragma unroll
        for (int i = 0; i < 8; ++i)
            gl2lds16(src + (size_t)i * (kN * 16), dst + i * 1024);
    };

    // ---- B tile read: quad (j,q) = chunk 2q+h, row j*32+l31 (conflict-free,
    // R21-proven addressing: two contiguous 512B runs per instruction).
    intx4 bl[2][4];
    auto ldsLoadT = [&]() {
        const unsigned char* base = &ldsB[wave][h * 1024 + l31 * 16];
        #pragma unroll
        for (int j = 0; j < 2; ++j)
            #pragma unroll
            for (int q = 0; q < 4; ++q)
                bl[j][q] = *(const intx4*)(base + q * 2048 + j * 512);
    };

    // one epi slice: 4 elems starting at vb (2 pk_fma + 4 cvt + 2 pk_add)
    auto epiQ = [&](const floatx16& ae, const int vb) {
        floatx2 t0 = {ae[vb + 0], ae[vb + 1]};
        floatx2 t1 = {ae[vb + 2], ae[vb + 3]};
        t0 = __builtin_elementwise_fma(t0, sc3v, bs3v);  // v_pk_fma_f32
        t1 = __builtin_elementwise_fma(t1, sc3v, bs3v);
        const intx2v e0 = {(int)t0.x, (int)t0.y};        // v_cvt_i32_f32
        const intx2v e1 = {(int)t1.x, (int)t1.y};
        sm0 += __builtin_bit_cast(floatx2, e0);          // v_pk_add_f32
        sm1 += __builtin_bit_cast(floatx2, e1);
    };

    // ---- main loop: barrier-free, wave-private single-buffered LDS.
    stageT(0);
    for (int s = 0; s < 32; ++s) {
        asm volatile("s_waitcnt vmcnt(0)" ::: "memory");   // stage(s) landed
        ldsLoadT();                                        // 8 ds_read_b128
        asm volatile("s_waitcnt lgkmcnt(0)" ::: "memory"); // reads done (WAR)
        if (s < 31) stageT(s + 1);                         // rewrite is now safe
        // M: 8 MFMAs (2 chains of 4, spacing 2) -- cross-wave TLP fills pipe
        #pragma unroll
        for (int q = 0; q < 4; ++q) {
            const intx8 a = U8(af[q]);
            acc[0] = MFMA4(a, U8(bl[0][q]), acc[0]);
            acc[1] = MFMA4(a, U8(bl[1][q]), acc[1]);
        }
        // E: 32 elems packed + diag + reset
        const int n0 = (cg + 8 * s) * 64;
        #pragma unroll
        for (int j = 0; j < 2; ++j) {
            epiQ(acc[j], 0); epiQ(acc[j], 4);
            epiQ(acc[j], 8); epiQ(acc[j], 12);
            if (rowBase == n0 + j * 32) {   // wave-uniform, rare
                #pragma unroll
                for (int v = 0; v < 16; ++v) {
                    const int rrow = (v & 3) + 8 * (v >> 2) + 4 * h;
                    if (rrow == l31) smd += fmaf(acc[j][v], sc, bs);
                }
            }
            acc[j] = (floatx16)(0.f);
        }
    }

    float sum = (sm0.x + sm1.x) + (sm0.y + sm1.y) - smd;

    // block reduce -> ONE atomicAdd per block (1024 total, spread in time)
    #pragma unroll
    for (int off = 32; off > 0; off >>= 1)
        sum += __shfl_down(sum, off);
    if (lane == 0) red[wave] = sum;
    __syncthreads();
    if (tid == 0) {
        float s2 = 0.f;
        #pragma unroll
        for (int w = 0; w < 4; ++w) s2 += red[w];
        atomicAdd(out, s2 * (1.0f / (float)kN));
    }
}

extern "C" void kernel_launch(void* const* d_in, const int* in_sizes, int n_in,
                              void* d_out, int out_size, void* d_ws, size_t ws_size,
                              hipStream_t stream) {
    const float* img     = (const float*)d_in[0];
    const float* txt     = (const float*)d_in[1];
    const float* scale_p = (const float*)d_in[2];
    const float* bias_p  = (const float*)d_in[3];
    float* out = (float*)d_out;

    unsigned char* Af4 = (unsigned char*)d_ws;            // N*KB = 2 MiB (row-major)
    unsigned char* Bf4 = Af4 + (size_t)kN * KB;           // 2 MiB (chunk-major)

    cvt_fp4_kernel<<<dim3(kN * kD / 8 / 256), dim3(256), 0, stream>>>(
        img, txt, (unsigned int*)Af4, (unsigned int*)Bf4, out);
    siglip_gemm_loss_kernel<<<dim3(1024), dim3(256), 0, stream>>>(
        Af4, Bf4, scale_p, bias_p, out);
}